// Round 20
// baseline (176.493 us; speedup 1.0000x reference)
//
#include <hip/hip_runtime.h>
#include <hip/hip_bf16.h>

// Problem constants
#define BB 2
#define TT 2048
#define DD 1024
#define HH 16
#define DH 64
#define RR 16
#define BT (BB*TT)      // 4096
#define BH (BB*HH)      // 32
#define D3 (3*DD)       // 3072
#define NC 1536         // fused GEMM1 N: 1024 V + 256 q_lr + 256 k_lr

typedef __bf16 bf16x8 __attribute__((ext_vector_type(8)));
typedef __bf16 bf16x4 __attribute__((ext_vector_type(4)));
typedef float f32x4 __attribute__((ext_vector_type(4)));
typedef short short4v __attribute__((ext_vector_type(4)));

__device__ __forceinline__ float bf2f(unsigned short u) {
  unsigned int v = ((unsigned int)u) << 16;
  return __builtin_bit_cast(float, v);
}
__device__ __forceinline__ unsigned short f2bf(float f) {
  unsigned int x = __builtin_bit_cast(unsigned int, f);
  unsigned int r = x + 0x7fffu + ((x >> 16) & 1u);
  return (unsigned short)(r >> 16);
}
__device__ __forceinline__ short4v pack_bf16x4(float a, float b, float c, float d) {
  uint2 u;
  u.x = (unsigned)f2bf(a) | ((unsigned)f2bf(b) << 16);
  u.y = (unsigned)f2bf(c) | ((unsigned)f2bf(d) << 16);
  return __builtin_bit_cast(short4v, u);
}
// compiler-cast pack: clang lowers f32->bf16 to HW v_cvt_pk_bf16_f32 on gfx950 (RTNE)
__device__ __forceinline__ short4v pack4_cvt(float a, float b, float c, float d) {
  bf16x4 v = {(__bf16)a, (__bf16)b, (__bf16)c, (__bf16)d};
  return __builtin_bit_cast(short4v, v);
}

#define NEG_BIG (-1e30f)

__device__ __forceinline__ void async_copy16(const void* g, void* l) {
  __builtin_amdgcn_global_load_lds((const __attribute__((address_space(1))) void*)g,
                                   (__attribute__((address_space(3))) void*)l, 16, 0, 0);
}

// ---------------- fused preprocessing: cvt + 2 transposes + build_lsr ---------------
__global__ __launch_bounds__(256) void prep_fused(const float* __restrict__ x,
                                                  const float* __restrict__ Wqkv,
                                                  const float* __restrict__ Wql,
                                                  const float* __restrict__ Wkl,
                                                  const float* __restrict__ core,
                                                  const float* __restrict__ Wo,
                                                  unsigned short* __restrict__ x_bf,
                                                  unsigned short* __restrict__ Wcomb_t,
                                                  unsigned short* __restrict__ Wo_t) {
  __shared__ float tile[32][33];
  __shared__ float Aq[64][65], Ak[64][65], Lq[64][16], Lk[64][16], cs[16];
  const int bid = blockIdx.x, tid = threadIdx.x;
  if (bid < 2048) {                       // ---- fp32 -> bf16 elementwise
    int i = (bid * 256 + tid) * 8;
    float4 a = *(const float4*)&x[i];
    float4 b = *(const float4*)&x[i + 4];
    unsigned short t[8] = {f2bf(a.x), f2bf(a.y), f2bf(a.z), f2bf(a.w),
                           f2bf(b.x), f2bf(b.y), f2bf(b.z), f2bf(b.w)};
    *(uint4*)&x_bf[i] = *(const uint4*)t;
  } else if (bid < 4096) {                // ---- transpose+cvt (two sources)
    const float* in; unsigned short* out; int C, coff, lb;
    if (bid < 3072) { in = Wo;   out = Wo_t;    C = DD; coff = 0;    lb = bid - 2048; }
    else            { in = Wqkv; out = Wcomb_t; C = D3; coff = 2048; lb = bid - 3072; }
    const int tx = tid & 31, ty = tid >> 5;
    const int bx = lb & 31, by = lb >> 5;
    const int xx = bx * 32 + tx, y0 = by * 32;
#pragma unroll
    for (int i = 0; i < 32; i += 8)
      tile[ty + i][tx] = in[(size_t)(y0 + ty + i) * C + coff + xx];
    __syncthreads();
    const int xo = y0 + tx, yo0 = bx * 32;
#pragma unroll
    for (int i = 0; i < 32; i += 8)
      out[(size_t)(yo0 + ty + i) * DD + xo] = f2bf(tile[tx][ty + i]);
  } else {                                // ---- build_lsr (Wcomb rows 1024..1535)
    const int l = bid - 4096;
    const int d0 = (l & 15) * 64, h = l >> 4;
#pragma unroll
    for (int p = 0; p < 16; p++) {
      int idx = p * 256 + tid, dd = idx >> 6, e = idx & 63;
      Aq[dd][e] = Wqkv[(size_t)(d0 + dd) * D3 + h * 64 + e];
      Ak[dd][e] = Wqkv[(size_t)(d0 + dd) * D3 + DD + h * 64 + e];
    }
#pragma unroll
    for (int p = 0; p < 4; p++) {
      int idx = p * 256 + tid, e = idx >> 4, r = idx & 15;
      Lq[e][r] = Wql[h * 1024 + e * 16 + r];
      Lk[e][r] = Wkl[h * 1024 + e * 16 + r];
    }
    if (tid < 16) cs[tid] = core[h * 16 + tid];
    __syncthreads();
    const int dd = tid & 63, rg = tid >> 6;
    float aq[4] = {}, ak[4] = {};
    for (int e = 0; e < 64; e++) {
      float xq = Aq[dd][e], xk = Ak[dd][e];
#pragma unroll
      for (int j = 0; j < 4; j++) {
        aq[j] += xq * Lq[e][rg * 4 + j];
        ak[j] += xk * Lk[e][rg * 4 + j];
      }
    }
#pragma unroll
    for (int j = 0; j < 4; j++) {
      int r = rg * 4 + j;
      // 0.25 = 1/sqrt(R); 1.4426950408889634 = log2(e) (exp -> exp2 in flash)
      Wcomb_t[(size_t)(1024 + h * 16 + r) * DD + d0 + dd] =
          f2bf(aq[j] * cs[r] * (0.25f * 1.4426950408889634f));
      Wcomb_t[(size_t)(1280 + h * 16 + r) * DD + d0 + dd] = f2bf(ak[j]);
    }
  }
}

// ---------------- bf16 GEMM core: 64x128 tile, 8 WAVES (512 thr), 2x BK32 panels ----
// (EXACT R17 body — equal-best proven GEMM.)
__device__ __forceinline__ void gemm64_core(const unsigned short* __restrict__ A,
                                            const unsigned short* __restrict__ Bt,
                                            int K, int bm, int bn,
                                            int tid, int g, int c, int wm, int wn,
                                            f32x4 acc[2][2]) {
  __shared__ __attribute__((aligned(16))) unsigned short As[2][2 * 2048];  // 2x8 KB
  __shared__ __attribute__((aligned(16))) unsigned short Bs[2][2 * 4096];  // 2x16 KB
  const int sa = tid * 8, ea = sa & 2047, pa = sa >> 11;
  const unsigned short* Aaddr = &A[(size_t)(bm * 64 + (ea >> 5)) * K + (ea & 31) + pa * 32];
  const int sb = tid * 8;
  const unsigned short* Baddr = &Bt[(size_t)(bn * 128 + (sb >> 5)) * K + (sb & 31)];
  async_copy16(Aaddr,      &As[0][sa]);
  async_copy16(Baddr,      &Bs[0][sb]);
  async_copy16(Baddr + 32, &Bs[0][4096 + sb]);
  __syncthreads();
  const int nsteps = K >> 6;               // 16 for K=1024
  for (int t = 0; t < nsteps; t++) {
    const int cur = t & 1, nxt = cur ^ 1;
    if (t + 1 < nsteps) {
      const int k1 = (t + 1) << 6;
      async_copy16(Aaddr + k1,      &As[nxt][sa]);
      async_copy16(Baddr + k1,      &Bs[nxt][sb]);
      async_copy16(Baddr + k1 + 32, &Bs[nxt][4096 + sb]);
    }
#pragma unroll
    for (int p = 0; p < 2; p++) {
      bf16x8 af[2], bf[2];
#pragma unroll
      for (int mt = 0; mt < 2; mt++)
        af[mt] = *(const bf16x8*)&As[cur][p * 2048 + (wm * 32 + mt * 16 + c) * 32 + g * 8];
#pragma unroll
      for (int nt = 0; nt < 2; nt++)
        bf[nt] = *(const bf16x8*)&Bs[cur][p * 4096 + (wn * 32 + nt * 16 + c) * 32 + g * 8];
#pragma unroll
      for (int nt = 0; nt < 2; nt++)
#pragma unroll
        for (int mt = 0; mt < 2; mt++)
          acc[mt][nt] = __builtin_amdgcn_mfma_f32_16x16x32_bf16(af[mt], bf[nt], acc[mt][nt], 0, 0, 0);
    }
    __syncthreads();
  }
}

// gemm2: C fp32 row-major. 1D grid 512, XCD-chunked swizzle (T1, proven R16 win).
__global__ __launch_bounds__(512) void gemm64_f32(const unsigned short* __restrict__ A,
                                                  const unsigned short* __restrict__ Bt,
                                                  float* __restrict__ C,
                                                  int M, int N, int K) {
  const int tid = threadIdx.x, lane = tid & 63;
  const int g = lane >> 4, c = lane & 15;
  const int wid = tid >> 6, wm = wid >> 2, wn = wid & 3;   // 8 waves: 2x4
  const int d = blockIdx.x;
  const int wg = (d & 7) * 64 + (d >> 3);
  const int bm = wg >> 3, bn = wg & 7;         // N/128 = 8
  f32x4 acc[2][2] = {};
  gemm64_core(A, Bt, K, bm, bn, tid, g, c, wm, wn, acc);
#pragma unroll
  for (int mt = 0; mt < 2; mt++)
#pragma unroll
    for (int nt = 0; nt < 2; nt++)
#pragma unroll
      for (int r = 0; r < 4; r++) {
        int row = bm * 64 + wm * 32 + mt * 16 + g * 4 + r;
        int col = bn * 128 + wn * 32 + nt * 16 + c;
        C[(size_t)row * N + col] = acc[mt][nt][r];
      }
}

// gemm1 fused: A = x_bf (4096x1024), Bt = Wcomb_t (1536x1024). 1D grid 768,
// XCD-chunked swizzle (768%8==0).
__global__ __launch_bounds__(512) void gemm_fused(const unsigned short* __restrict__ A,
                                                  const unsigned short* __restrict__ Bt,
                                                  unsigned short* __restrict__ qls,
                                                  unsigned short* __restrict__ klr,
                                                  unsigned short* __restrict__ vt,
                                                  int M, int N, int K) {
  const int tid = threadIdx.x, lane = tid & 63;
  const int g = lane >> 4, c = lane & 15;
  const int wid = tid >> 6, wm = wid >> 2, wn = wid & 3;   // 8 waves: 2x4
  const int d = blockIdx.x;
  const int wg = (d & 7) * 96 + (d >> 3);
  const int bm = wg / 12, bn = wg % 12;        // N/128 = 12
  f32x4 acc[2][2] = {};
  gemm64_core(A, Bt, K, bm, bn, tid, g, c, wm, wn, acc);
#pragma unroll
  for (int mt = 0; mt < 2; mt++)
#pragma unroll
    for (int nt = 0; nt < 2; nt++) {
      int colb = bn * 128 + wn * 32 + nt * 16;        // + c (16-aligned origin)
      int tg0 = bm * 64 + wm * 32 + mt * 16 + g * 4;  // tokens tg0..tg0+3 (4-aligned)
      int b = tg0 >> 11, t0 = tg0 & 2047;
      if (colb < 1024) {
        int h = colb >> 6, d2 = (colb & 63) + c;
        uint2 pk = __builtin_bit_cast(uint2, pack_bf16x4(acc[mt][nt][0], acc[mt][nt][1],
                                                         acc[mt][nt][2], acc[mt][nt][3]));
        size_t idx = (size_t)(b * 16 + h) * (TT / 4) * 256 + (size_t)(t0 >> 2) * 256 + d2 * 4;
        *(uint2*)&vt[idx] = pk;
      } else if (colb < 1280) {
        int h = (colb - 1024) >> 4;
        size_t base = (size_t)(b * 16 + h) * TT;
#pragma unroll
        for (int r = 0; r < 4; r++)
          qls[(base + t0 + r) * 16 + c] = f2bf(acc[mt][nt][r]);
      } else {
        int h = (colb - 1280) >> 4;
        size_t base = (size_t)(b * 16 + h) * TT;
#pragma unroll
        for (int r = 0; r < 4; r++)
          klr[(base + t0 + r) * 16 + c] = f2bf(acc[mt][nt][r]);
      }
    }
}

// ---------------- Flash attention v19: v14 body + T5 s_setprio on MFMA clusters -----
// v14 = dual 16-row q-chunks, balanced qt pairing, K LDS dbuf + reg prefetch, V from
// L2, exp2 softmax, O^T layout (proven 44.4us). T5: wrap the QK and PV MFMA clusters
// in setprio(1)/(0). Mechanism (m191, +4-7% attn): co-resident blocks run at
// independent phases; raising priority while feeding the matrix pipe lets the CU
// scheduler favor MFMA-issuing waves over load-issuing ones. Two intrinsics per
// cluster — no branches, no extra state, no codegen risk.
__global__ __launch_bounds__(256, 2) void flash_lsr(const unsigned short* __restrict__ qls,
                                                    const unsigned short* __restrict__ klr,
                                                    const unsigned short* __restrict__ vt,
                                                    unsigned short* __restrict__ attn) {
  const int bh = blockIdx.x & 31, b = bh >> 4, h = bh & 15;
  const int i = blockIdx.x >> 5;                   // 0..15
  const int qt = (i < 8) ? (15 - i) : (i - 8);     // balanced CU pairs: (15,0)..(8,7)
  const int tid = threadIdx.x, lane = tid & 63, w = tid >> 6;
  const int g = lane >> 4, c = lane & 15;
  const int q0 = qt * 128, jmax = qt;

  __shared__ __attribute__((aligned(16))) unsigned short Ks[2][128 * 20];  // 2x5.0 KB

  const size_t qbase = (size_t)bh * TT;
  const short4v qfA = __builtin_bit_cast(short4v,
      *(const uint2*)&qls[(qbase + q0 + w * 16 + c) * 16 + g * 4]);
  const short4v qfB = __builtin_bit_cast(short4v,
      *(const uint2*)&qls[(qbase + q0 + 64 + w * 16 + c) * 16 + g * 4]);
  const int qgA = q0 + w * 16 + c, qgB = qgA + 64;
  float miA = NEG_BIG, liA = 0.f, miB = NEG_BIG, liB = 0.f;
  f32x4 oaA[4] = {}, oaB[4] = {};
  const f32x4 zero = {0.f, 0.f, 0.f, 0.f};
  const size_t kb = (size_t)bh * TT * 16;
  const size_t vb = (size_t)bh * TT * 64;

  // prefetch K j-tile 0 into registers
  uint4 kr = *(const uint4*)&klr[kb + tid * 8];

  int p = 0;
  f32x4 sA[8], sB[8];
  for (int jt = 0; jt <= jmax; jt++) {
    *(uint4*)&Ks[p][(tid >> 1) * 20 + (tid & 1) * 8] = kr;
    __syncthreads();
    if (jt < jmax)   // register prefetch of next K tile overlaps compute
      kr = *(const uint4*)&klr[kb + (size_t)(jt + 1) * 2048 + tid * 8];
    // QK^T: each kf feeds both chunks. s[nt][r] = score(j=jt*128+nt*16+g*4+r, q)
    const unsigned short* Kb = Ks[p];
    __builtin_amdgcn_s_setprio(1);           // T5: favor MFMA-feeding wave
#pragma unroll
    for (int nt = 0; nt < 8; nt++) {
      short4v kf = __builtin_bit_cast(short4v, *(const uint2*)&Kb[(nt * 16 + c) * 20 + g * 4]);
      sA[nt] = __builtin_amdgcn_mfma_f32_16x16x16bf16_1k(kf, qfA, zero, 0, 0, 0);
      sB[nt] = __builtin_amdgcn_mfma_f32_16x16x16bf16_1k(kf, qfB, zero, 0, 0, 0);
    }
    __builtin_amdgcn_s_setprio(0);
    if (jt == jmax) {  // causal mask: only the diagonal tile, both chunks
#pragma unroll
      for (int nt = 0; nt < 8; nt++)
#pragma unroll
        for (int r = 0; r < 4; r++) {
          int jg = jt * 128 + nt * 16 + g * 4 + r;
          if (jg > qgA) sA[nt][r] = NEG_BIG;
          if (jg > qgB) sB[nt][r] = NEG_BIG;
        }
    }
    // online softmax (exp2 domain), two independent chains — compiler interleaves
    auto softmax = [&](f32x4 (&s)[8], float& mi, float& li, f32x4 (&oa)[4]) {
      f32x4 vm = s[0];
#pragma unroll
      for (int nt = 1; nt < 8; nt++)
#pragma unroll
        for (int r = 0; r < 4; r++) vm[r] = fmaxf(vm[r], s[nt][r]);
      float rm = fmaxf(fmaxf(vm[0], vm[1]), fmaxf(vm[2], vm[3]));
      rm = fmaxf(rm, __shfl_xor(rm, 16, 64));
      rm = fmaxf(rm, __shfl_xor(rm, 32, 64));
      float mnew = fmaxf(mi, rm);
      float alpha = __builtin_amdgcn_exp2f(mi - mnew);
      mi = mnew;
      f32x4 vs = zero;
#pragma unroll
      for (int nt = 0; nt < 8; nt++)
#pragma unroll
        for (int r = 0; r < 4; r++) {
          float pv = __builtin_amdgcn_exp2f(s[nt][r] - mnew);
          s[nt][r] = pv;
          vs[r] += pv;
        }
      float rs = (vs[0] + vs[1]) + (vs[2] + vs[3]);
      rs += __shfl_xor(rs, 16, 64);
      rs += __shfl_xor(rs, 32, 64);
      li = li * alpha + rs;
#pragma unroll
      for (int nd = 0; nd < 4; nd++)
#pragma unroll
        for (int r = 0; r < 4; r++) oa[nd][r] *= alpha;  // O^T col = q = c
    };
    softmax(sA, miA, liA, oaA);
    softmax(sB, miB, liB, oaB);
    // PV: O^T = mfma(V, P); each V fragment (L2-resident) feeds both chunks
    const unsigned short* vp = &vt[vb + (size_t)jt * 8192];
    __builtin_amdgcn_s_setprio(1);           // T5
#pragma unroll
    for (int kc = 0; kc < 8; kc++) {
      short4v pfA = pack4_cvt(sA[kc][0], sA[kc][1], sA[kc][2], sA[kc][3]);
      short4v pfB = pack4_cvt(sB[kc][0], sB[kc][1], sB[kc][2], sB[kc][3]);
#pragma unroll
      for (int nd = 0; nd < 4; nd++) {
        uint2 vv = *(const uint2*)&vp[(kc * 4 + g) * 256 + (nd * 16 + c) * 4];
        short4v vf = __builtin_bit_cast(short4v, vv);
        oaA[nd] = __builtin_amdgcn_mfma_f32_16x16x16bf16_1k(vf, pfA, oaA[nd], 0, 0, 0);
        oaB[nd] = __builtin_amdgcn_mfma_f32_16x16x16bf16_1k(vf, pfB, oaB[nd], 0, 0, 0);
      }
    }
    __builtin_amdgcn_s_setprio(0);
    p ^= 1;
  }

  // epilogue: O^T[d = nd*16 + g*4 + r][q = c]; per-thread 1/li; contiguous stores
  const float invA = 1.f / liA, invB = 1.f / liB;
  const size_t rowA = ((size_t)b * TT + q0 + w * 16 + c) * DD + h * 64;
  const size_t rowB = rowA + (size_t)64 * DD;
#pragma unroll
  for (int nd = 0; nd < 4; nd++) {
    short4v pkA = pack4_cvt(oaA[nd][0] * invA, oaA[nd][1] * invA,
                            oaA[nd][2] * invA, oaA[nd][3] * invA);
    *(uint2*)&attn[rowA + nd * 16 + g * 4] = __builtin_bit_cast(uint2, pkA);
    short4v pkB = pack4_cvt(oaB[nd][0] * invB, oaB[nd][1] * invB,
                            oaB[nd][2] * invB, oaB[nd][3] * invB);
    *(uint2*)&attn[rowB + nd * 16 + g * 4] = __builtin_bit_cast(uint2, pkB);
  }
}

extern "C" void kernel_launch(void* const* d_in, const int* in_sizes, int n_in,
                              void* d_out, int out_size, void* d_ws, size_t ws_size,
                              hipStream_t stream) {
  const float* x      = (const float*)d_in[0];  // (B,T,1024) fp32
  const float* W_qkv  = (const float*)d_in[1];  // (1024,3072) fp32
  const float* W_qlsr = (const float*)d_in[2];  // (16,64,16)  fp32
  const float* W_klsr = (const float*)d_in[3];  // (16,64,16)  fp32
  const float* core   = (const float*)d_in[4];  // (16,16)     fp32
  const float* W_o    = (const float*)d_in[5];  // (1024,1024) fp32
  float* out = (float*)d_out;                   // (B,T,1024)  fp32

  char* ws = (char*)d_ws;
  unsigned short* x_bf    = (unsigned short*)ws; ws += (size_t)BT * DD * 2;
  unsigned short* Wcomb_t = (unsigned short*)ws; ws += (size_t)NC * DD * 2;
  unsigned short* Wo_t    = (unsigned short*)ws; ws += (size_t)DD * DD * 2;
  unsigned short* qls     = (unsigned short*)ws; ws += (size_t)BH * TT * 16 * 2;
  unsigned short* klr     = (unsigned short*)ws; ws += (size_t)BH * TT * 16 * 2;
  unsigned short* vt      = (unsigned short*)ws; ws += (size_t)BH * TT * 64 * 2;
  unsigned short* attn    = (unsigned short*)ws; ws += (size_t)BT * DD * 2;

  prep_fused<<<4352, 256, 0, stream>>>(x, W_qkv, W_qlsr, W_klsr, core, W_o,
                                       x_bf, Wcomb_t, Wo_t);
  gemm_fused<<<768, 512, 0, stream>>>(x_bf, Wcomb_t, qls, klr, vt, BT, NC, DD);
  flash_lsr<<<dim3(16 * BH), 256, 0, stream>>>(qls, klr, vt, attn);
  gemm64_f32<<<512, 512, 0, stream>>>(attn, Wo_t, out, BT, DD, DD);
}

// Round 21
// 162.320 us; speedup vs baseline: 1.0873x; 1.0873x over previous
//
#include <hip/hip_runtime.h>
#include <hip/hip_bf16.h>

// Problem constants
#define BB 2
#define TT 2048
#define DD 1024
#define HH 16
#define DH 64
#define RR 16
#define BT (BB*TT)      // 4096
#define BH (BB*HH)      // 32
#define D3 (3*DD)       // 3072
#define NC 1536         // fused GEMM1 N: 1024 V + 256 q_lr + 256 k_lr

typedef __bf16 bf16x8 __attribute__((ext_vector_type(8)));
typedef __bf16 bf16x4 __attribute__((ext_vector_type(4)));
typedef float f32x4 __attribute__((ext_vector_type(4)));
typedef short short4v __attribute__((ext_vector_type(4)));

__device__ __forceinline__ float bf2f(unsigned short u) {
  unsigned int v = ((unsigned int)u) << 16;
  return __builtin_bit_cast(float, v);
}
__device__ __forceinline__ unsigned short f2bf(float f) {
  unsigned int x = __builtin_bit_cast(unsigned int, f);
  unsigned int r = x + 0x7fffu + ((x >> 16) & 1u);
  return (unsigned short)(r >> 16);
}
__device__ __forceinline__ short4v pack_bf16x4(float a, float b, float c, float d) {
  uint2 u;
  u.x = (unsigned)f2bf(a) | ((unsigned)f2bf(b) << 16);
  u.y = (unsigned)f2bf(c) | ((unsigned)f2bf(d) << 16);
  return __builtin_bit_cast(short4v, u);
}
// compiler-cast pack: clang lowers f32->bf16 to HW v_cvt_pk_bf16_f32 on gfx950 (RTNE)
__device__ __forceinline__ short4v pack4_cvt(float a, float b, float c, float d) {
  bf16x4 v = {(__bf16)a, (__bf16)b, (__bf16)c, (__bf16)d};
  return __builtin_bit_cast(short4v, v);
}

#define NEG_BIG (-1e30f)

__device__ __forceinline__ void async_copy16(const void* g, void* l) {
  __builtin_amdgcn_global_load_lds((const __attribute__((address_space(1))) void*)g,
                                   (__attribute__((address_space(3))) void*)l, 16, 0, 0);
}

// ---------------- fused preprocessing: cvt + 2 transposes + build_lsr ---------------
__global__ __launch_bounds__(256) void prep_fused(const float* __restrict__ x,
                                                  const float* __restrict__ Wqkv,
                                                  const float* __restrict__ Wql,
                                                  const float* __restrict__ Wkl,
                                                  const float* __restrict__ core,
                                                  const float* __restrict__ Wo,
                                                  unsigned short* __restrict__ x_bf,
                                                  unsigned short* __restrict__ Wcomb_t,
                                                  unsigned short* __restrict__ Wo_t) {
  __shared__ float tile[32][33];
  __shared__ float Aq[64][65], Ak[64][65], Lq[64][16], Lk[64][16], cs[16];
  const int bid = blockIdx.x, tid = threadIdx.x;
  if (bid < 2048) {                       // ---- fp32 -> bf16 elementwise
    int i = (bid * 256 + tid) * 8;
    float4 a = *(const float4*)&x[i];
    float4 b = *(const float4*)&x[i + 4];
    unsigned short t[8] = {f2bf(a.x), f2bf(a.y), f2bf(a.z), f2bf(a.w),
                           f2bf(b.x), f2bf(b.y), f2bf(b.z), f2bf(b.w)};
    *(uint4*)&x_bf[i] = *(const uint4*)t;
  } else if (bid < 4096) {                // ---- transpose+cvt (two sources)
    const float* in; unsigned short* out; int C, coff, lb;
    if (bid < 3072) { in = Wo;   out = Wo_t;    C = DD; coff = 0;    lb = bid - 2048; }
    else            { in = Wqkv; out = Wcomb_t; C = D3; coff = 2048; lb = bid - 3072; }
    const int tx = tid & 31, ty = tid >> 5;
    const int bx = lb & 31, by = lb >> 5;
    const int xx = bx * 32 + tx, y0 = by * 32;
#pragma unroll
    for (int i = 0; i < 32; i += 8)
      tile[ty + i][tx] = in[(size_t)(y0 + ty + i) * C + coff + xx];
    __syncthreads();
    const int xo = y0 + tx, yo0 = bx * 32;
#pragma unroll
    for (int i = 0; i < 32; i += 8)
      out[(size_t)(yo0 + ty + i) * DD + xo] = f2bf(tile[tx][ty + i]);
  } else {                                // ---- build_lsr (Wcomb rows 1024..1535)
    const int l = bid - 4096;
    const int d0 = (l & 15) * 64, h = l >> 4;
#pragma unroll
    for (int p = 0; p < 16; p++) {
      int idx = p * 256 + tid, dd = idx >> 6, e = idx & 63;
      Aq[dd][e] = Wqkv[(size_t)(d0 + dd) * D3 + h * 64 + e];
      Ak[dd][e] = Wqkv[(size_t)(d0 + dd) * D3 + DD + h * 64 + e];
    }
#pragma unroll
    for (int p = 0; p < 4; p++) {
      int idx = p * 256 + tid, e = idx >> 4, r = idx & 15;
      Lq[e][r] = Wql[h * 1024 + e * 16 + r];
      Lk[e][r] = Wkl[h * 1024 + e * 16 + r];
    }
    if (tid < 16) cs[tid] = core[h * 16 + tid];
    __syncthreads();
    const int dd = tid & 63, rg = tid >> 6;
    float aq[4] = {}, ak[4] = {};
    for (int e = 0; e < 64; e++) {
      float xq = Aq[dd][e], xk = Ak[dd][e];
#pragma unroll
      for (int j = 0; j < 4; j++) {
        aq[j] += xq * Lq[e][rg * 4 + j];
        ak[j] += xk * Lk[e][rg * 4 + j];
      }
    }
#pragma unroll
    for (int j = 0; j < 4; j++) {
      int r = rg * 4 + j;
      // 0.25 = 1/sqrt(R); 1.4426950408889634 = log2(e) (exp -> exp2 in flash)
      Wcomb_t[(size_t)(1024 + h * 16 + r) * DD + d0 + dd] =
          f2bf(aq[j] * cs[r] * (0.25f * 1.4426950408889634f));
      Wcomb_t[(size_t)(1280 + h * 16 + r) * DD + d0 + dd] = f2bf(ak[j]);
    }
  }
}

// ---------------- bf16 GEMM core: 64x128 tile, 8 WAVES (512 thr), 2x BK32 panels ----
// (EXACT R17 body — best proven GEMM across 7 structural variants.)
__device__ __forceinline__ void gemm64_core(const unsigned short* __restrict__ A,
                                            const unsigned short* __restrict__ Bt,
                                            int K, int bm, int bn,
                                            int tid, int g, int c, int wm, int wn,
                                            f32x4 acc[2][2]) {
  __shared__ __attribute__((aligned(16))) unsigned short As[2][2 * 2048];  // 2x8 KB
  __shared__ __attribute__((aligned(16))) unsigned short Bs[2][2 * 4096];  // 2x16 KB
  const int sa = tid * 8, ea = sa & 2047, pa = sa >> 11;
  const unsigned short* Aaddr = &A[(size_t)(bm * 64 + (ea >> 5)) * K + (ea & 31) + pa * 32];
  const int sb = tid * 8;
  const unsigned short* Baddr = &Bt[(size_t)(bn * 128 + (sb >> 5)) * K + (sb & 31)];
  async_copy16(Aaddr,      &As[0][sa]);
  async_copy16(Baddr,      &Bs[0][sb]);
  async_copy16(Baddr + 32, &Bs[0][4096 + sb]);
  __syncthreads();
  const int nsteps = K >> 6;               // 16 for K=1024
  for (int t = 0; t < nsteps; t++) {
    const int cur = t & 1, nxt = cur ^ 1;
    if (t + 1 < nsteps) {
      const int k1 = (t + 1) << 6;
      async_copy16(Aaddr + k1,      &As[nxt][sa]);
      async_copy16(Baddr + k1,      &Bs[nxt][sb]);
      async_copy16(Baddr + k1 + 32, &Bs[nxt][4096 + sb]);
    }
#pragma unroll
    for (int p = 0; p < 2; p++) {
      bf16x8 af[2], bf[2];
#pragma unroll
      for (int mt = 0; mt < 2; mt++)
        af[mt] = *(const bf16x8*)&As[cur][p * 2048 + (wm * 32 + mt * 16 + c) * 32 + g * 8];
#pragma unroll
      for (int nt = 0; nt < 2; nt++)
        bf[nt] = *(const bf16x8*)&Bs[cur][p * 4096 + (wn * 32 + nt * 16 + c) * 32 + g * 8];
#pragma unroll
      for (int nt = 0; nt < 2; nt++)
#pragma unroll
        for (int mt = 0; mt < 2; mt++)
          acc[mt][nt] = __builtin_amdgcn_mfma_f32_16x16x32_bf16(af[mt], bf[nt], acc[mt][nt], 0, 0, 0);
    }
    __syncthreads();
  }
}

// gemm2: C fp32 row-major. 1D grid 512, XCD-chunked swizzle (T1, proven R16 win).
__global__ __launch_bounds__(512) void gemm64_f32(const unsigned short* __restrict__ A,
                                                  const unsigned short* __restrict__ Bt,
                                                  float* __restrict__ C,
                                                  int M, int N, int K) {
  const int tid = threadIdx.x, lane = tid & 63;
  const int g = lane >> 4, c = lane & 15;
  const int wid = tid >> 6, wm = wid >> 2, wn = wid & 3;   // 8 waves: 2x4
  const int d = blockIdx.x;
  const int wg = (d & 7) * 64 + (d >> 3);
  const int bm = wg >> 3, bn = wg & 7;         // N/128 = 8
  f32x4 acc[2][2] = {};
  gemm64_core(A, Bt, K, bm, bn, tid, g, c, wm, wn, acc);
#pragma unroll
  for (int mt = 0; mt < 2; mt++)
#pragma unroll
    for (int nt = 0; nt < 2; nt++)
#pragma unroll
      for (int r = 0; r < 4; r++) {
        int row = bm * 64 + wm * 32 + mt * 16 + g * 4 + r;
        int col = bn * 128 + wn * 32 + nt * 16 + c;
        C[(size_t)row * N + col] = acc[mt][nt][r];
      }
}

// gemm1 fused: A = x_bf (4096x1024), Bt = Wcomb_t (1536x1024). 1D grid 768,
// XCD-chunked swizzle (768%8==0).
__global__ __launch_bounds__(512) void gemm_fused(const unsigned short* __restrict__ A,
                                                  const unsigned short* __restrict__ Bt,
                                                  unsigned short* __restrict__ qls,
                                                  unsigned short* __restrict__ klr,
                                                  unsigned short* __restrict__ vt,
                                                  int M, int N, int K) {
  const int tid = threadIdx.x, lane = tid & 63;
  const int g = lane >> 4, c = lane & 15;
  const int wid = tid >> 6, wm = wid >> 2, wn = wid & 3;   // 8 waves: 2x4
  const int d = blockIdx.x;
  const int wg = (d & 7) * 96 + (d >> 3);
  const int bm = wg / 12, bn = wg % 12;        // N/128 = 12
  f32x4 acc[2][2] = {};
  gemm64_core(A, Bt, K, bm, bn, tid, g, c, wm, wn, acc);
#pragma unroll
  for (int mt = 0; mt < 2; mt++)
#pragma unroll
    for (int nt = 0; nt < 2; nt++) {
      int colb = bn * 128 + wn * 32 + nt * 16;        // + c (16-aligned origin)
      int tg0 = bm * 64 + wm * 32 + mt * 16 + g * 4;  // tokens tg0..tg0+3 (4-aligned)
      int b = tg0 >> 11, t0 = tg0 & 2047;
      if (colb < 1024) {
        int h = colb >> 6, d2 = (colb & 63) + c;
        uint2 pk = __builtin_bit_cast(uint2, pack_bf16x4(acc[mt][nt][0], acc[mt][nt][1],
                                                         acc[mt][nt][2], acc[mt][nt][3]));
        size_t idx = (size_t)(b * 16 + h) * (TT / 4) * 256 + (size_t)(t0 >> 2) * 256 + d2 * 4;
        *(uint2*)&vt[idx] = pk;
      } else if (colb < 1280) {
        int h = (colb - 1024) >> 4;
        size_t base = (size_t)(b * 16 + h) * TT;
#pragma unroll
        for (int r = 0; r < 4; r++)
          qls[(base + t0 + r) * 16 + c] = f2bf(acc[mt][nt][r]);
      } else {
        int h = (colb - 1280) >> 4;
        size_t base = (size_t)(b * 16 + h) * TT;
#pragma unroll
        for (int r = 0; r < 4; r++)
          klr[(base + t0 + r) * 16 + c] = f2bf(acc[mt][nt][r]);
      }
    }
}

// ---------------- Flash attention v14 (EXACT R16/R17/R19 body, proven 44.4us) -------
// Dual 16-row q-chunks per wave on a 128-row tile; balanced qt pairing; K LDS dbuf
// + register prefetch; V direct from L2; exp2 softmax; O^T layout (per-thread
// alpha/1li). T5 setprio (R20) REVERTED: broke softmax-chain interleaving
// (VGPR 96->88, MfmaUtil 18.5->15.4, 44.4->52.8us).
__global__ __launch_bounds__(256, 2) void flash_lsr(const unsigned short* __restrict__ qls,
                                                    const unsigned short* __restrict__ klr,
                                                    const unsigned short* __restrict__ vt,
                                                    unsigned short* __restrict__ attn) {
  const int bh = blockIdx.x & 31, b = bh >> 4, h = bh & 15;
  const int i = blockIdx.x >> 5;                   // 0..15
  const int qt = (i < 8) ? (15 - i) : (i - 8);     // balanced CU pairs: (15,0)..(8,7)
  const int tid = threadIdx.x, lane = tid & 63, w = tid >> 6;
  const int g = lane >> 4, c = lane & 15;
  const int q0 = qt * 128, jmax = qt;

  __shared__ __attribute__((aligned(16))) unsigned short Ks[2][128 * 20];  // 2x5.0 KB

  const size_t qbase = (size_t)bh * TT;
  const short4v qfA = __builtin_bit_cast(short4v,
      *(const uint2*)&qls[(qbase + q0 + w * 16 + c) * 16 + g * 4]);
  const short4v qfB = __builtin_bit_cast(short4v,
      *(const uint2*)&qls[(qbase + q0 + 64 + w * 16 + c) * 16 + g * 4]);
  const int qgA = q0 + w * 16 + c, qgB = qgA + 64;
  float miA = NEG_BIG, liA = 0.f, miB = NEG_BIG, liB = 0.f;
  f32x4 oaA[4] = {}, oaB[4] = {};
  const f32x4 zero = {0.f, 0.f, 0.f, 0.f};
  const size_t kb = (size_t)bh * TT * 16;
  const size_t vb = (size_t)bh * TT * 64;

  // prefetch K j-tile 0 into registers
  uint4 kr = *(const uint4*)&klr[kb + tid * 8];

  int p = 0;
  f32x4 sA[8], sB[8];
  for (int jt = 0; jt <= jmax; jt++) {
    *(uint4*)&Ks[p][(tid >> 1) * 20 + (tid & 1) * 8] = kr;
    __syncthreads();
    if (jt < jmax)   // register prefetch of next K tile overlaps compute
      kr = *(const uint4*)&klr[kb + (size_t)(jt + 1) * 2048 + tid * 8];
    // QK^T: each kf feeds both chunks. s[nt][r] = score(j=jt*128+nt*16+g*4+r, q)
    const unsigned short* Kb = Ks[p];
#pragma unroll
    for (int nt = 0; nt < 8; nt++) {
      short4v kf = __builtin_bit_cast(short4v, *(const uint2*)&Kb[(nt * 16 + c) * 20 + g * 4]);
      sA[nt] = __builtin_amdgcn_mfma_f32_16x16x16bf16_1k(kf, qfA, zero, 0, 0, 0);
      sB[nt] = __builtin_amdgcn_mfma_f32_16x16x16bf16_1k(kf, qfB, zero, 0, 0, 0);
    }
    if (jt == jmax) {  // causal mask: only the diagonal tile, both chunks
#pragma unroll
      for (int nt = 0; nt < 8; nt++)
#pragma unroll
        for (int r = 0; r < 4; r++) {
          int jg = jt * 128 + nt * 16 + g * 4 + r;
          if (jg > qgA) sA[nt][r] = NEG_BIG;
          if (jg > qgB) sB[nt][r] = NEG_BIG;
        }
    }
    // online softmax (exp2 domain), two independent chains — compiler interleaves
    auto softmax = [&](f32x4 (&s)[8], float& mi, float& li, f32x4 (&oa)[4]) {
      f32x4 vm = s[0];
#pragma unroll
      for (int nt = 1; nt < 8; nt++)
#pragma unroll
        for (int r = 0; r < 4; r++) vm[r] = fmaxf(vm[r], s[nt][r]);
      float rm = fmaxf(fmaxf(vm[0], vm[1]), fmaxf(vm[2], vm[3]));
      rm = fmaxf(rm, __shfl_xor(rm, 16, 64));
      rm = fmaxf(rm, __shfl_xor(rm, 32, 64));
      float mnew = fmaxf(mi, rm);
      float alpha = __builtin_amdgcn_exp2f(mi - mnew);
      mi = mnew;
      f32x4 vs = zero;
#pragma unroll
      for (int nt = 0; nt < 8; nt++)
#pragma unroll
        for (int r = 0; r < 4; r++) {
          float pv = __builtin_amdgcn_exp2f(s[nt][r] - mnew);
          s[nt][r] = pv;
          vs[r] += pv;
        }
      float rs = (vs[0] + vs[1]) + (vs[2] + vs[3]);
      rs += __shfl_xor(rs, 16, 64);
      rs += __shfl_xor(rs, 32, 64);
      li = li * alpha + rs;
#pragma unroll
      for (int nd = 0; nd < 4; nd++)
#pragma unroll
        for (int r = 0; r < 4; r++) oa[nd][r] *= alpha;  // O^T col = q = c
    };
    softmax(sA, miA, liA, oaA);
    softmax(sB, miB, liB, oaB);
    // PV: O^T = mfma(V, P); each V fragment (L2-resident) feeds both chunks
    const unsigned short* vp = &vt[vb + (size_t)jt * 8192];
#pragma unroll
    for (int kc = 0; kc < 8; kc++) {
      short4v pfA = pack4_cvt(sA[kc][0], sA[kc][1], sA[kc][2], sA[kc][3]);
      short4v pfB = pack4_cvt(sB[kc][0], sB[kc][1], sB[kc][2], sB[kc][3]);
#pragma unroll
      for (int nd = 0; nd < 4; nd++) {
        uint2 vv = *(const uint2*)&vp[(kc * 4 + g) * 256 + (nd * 16 + c) * 4];
        short4v vf = __builtin_bit_cast(short4v, vv);
        oaA[nd] = __builtin_amdgcn_mfma_f32_16x16x16bf16_1k(vf, pfA, oaA[nd], 0, 0, 0);
        oaB[nd] = __builtin_amdgcn_mfma_f32_16x16x16bf16_1k(vf, pfB, oaB[nd], 0, 0, 0);
      }
    }
    p ^= 1;
  }

  // epilogue: O^T[d = nd*16 + g*4 + r][q = c]; per-thread 1/li; contiguous stores
  const float invA = 1.f / liA, invB = 1.f / liB;
  const size_t rowA = ((size_t)b * TT + q0 + w * 16 + c) * DD + h * 64;
  const size_t rowB = rowA + (size_t)64 * DD;
#pragma unroll
  for (int nd = 0; nd < 4; nd++) {
    short4v pkA = pack4_cvt(oaA[nd][0] * invA, oaA[nd][1] * invA,
                            oaA[nd][2] * invA, oaA[nd][3] * invA);
    *(uint2*)&attn[rowA + nd * 16 + g * 4] = __builtin_bit_cast(uint2, pkA);
    short4v pkB = pack4_cvt(oaB[nd][0] * invB, oaB[nd][1] * invB,
                            oaB[nd][2] * invB, oaB[nd][3] * invB);
    *(uint2*)&attn[rowB + nd * 16 + g * 4] = __builtin_bit_cast(uint2, pkB);
  }
}

extern "C" void kernel_launch(void* const* d_in, const int* in_sizes, int n_in,
                              void* d_out, int out_size, void* d_ws, size_t ws_size,
                              hipStream_t stream) {
  const float* x      = (const float*)d_in[0];  // (B,T,1024) fp32
  const float* W_qkv  = (const float*)d_in[1];  // (1024,3072) fp32
  const float* W_qlsr = (const float*)d_in[2];  // (16,64,16)  fp32
  const float* W_klsr = (const float*)d_in[3];  // (16,64,16)  fp32
  const float* core   = (const float*)d_in[4];  // (16,16)     fp32
  const float* W_o    = (const float*)d_in[5];  // (1024,1024) fp32
  float* out = (float*)d_out;                   // (B,T,1024)  fp32

  char* ws = (char*)d_ws;
  unsigned short* x_bf    = (unsigned short*)ws; ws += (size_t)BT * DD * 2;
  unsigned short* Wcomb_t = (unsigned short*)ws; ws += (size_t)NC * DD * 2;
  unsigned short* Wo_t    = (unsigned short*)ws; ws += (size_t)DD * DD * 2;
  unsigned short* qls     = (unsigned short*)ws; ws += (size_t)BH * TT * 16 * 2;
  unsigned short* klr     = (unsigned short*)ws; ws += (size_t)BH * TT * 16 * 2;
  unsigned short* vt      = (unsigned short*)ws; ws += (size_t)BH * TT * 64 * 2;
  unsigned short* attn    = (unsigned short*)ws; ws += (size_t)BT * DD * 2;

  prep_fused<<<4352, 256, 0, stream>>>(x, W_qkv, W_qlsr, W_klsr, core, W_o,
                                       x_bf, Wcomb_t, Wo_t);
  gemm_fused<<<768, 512, 0, stream>>>(x_bf, Wcomb_t, qls, klr, vt, BT, NC, DD);
  flash_lsr<<<dim3(16 * BH), 256, 0, stream>>>(qls, klr, vt, attn);
  gemm64_f32<<<512, 512, 0, stream>>>(attn, Wo_t, out, BT, DD, DD);
}